// Round 1
// baseline (166.981 us; speedup 1.0000x reference)
//
#include <hip/hip_runtime.h>

#define B_ 8
#define T_ 1024
#define C_ 768
#define H_ 12
#define D_ 64
#define M_ (B_*T_)      // 8192 rows
#define N3_ (3*C_)      // 2304

typedef __bf16 bf16x8 __attribute__((ext_vector_type(8)));
typedef float f32x4 __attribute__((ext_vector_type(4)));

__device__ __forceinline__ ushort f2bf(float f){
  union { float f; unsigned u; } v; v.f = f;
  unsigned r = (v.u + 0x7FFFu + ((v.u >> 16) & 1u)) >> 16;
  return (ushort)r;
}
__device__ __forceinline__ float bf2f(ushort h){
  union { unsigned u; float f; } v; v.u = ((unsigned)h) << 16;
  return v.f;
}

// ---- fp32 -> bf16 elementwise (n % 4 == 0) ----
__global__ void cvt_f32_bf16(const float* __restrict__ in, ushort* __restrict__ out, int n){
  int i = (blockIdx.x * blockDim.x + threadIdx.x) * 4;
  if (i >= n) return;
  float4 f = *(const float4*)(in + i);
  ushort4 o = { f2bf(f.x), f2bf(f.y), f2bf(f.z), f2bf(f.w) };
  *(ushort4*)(out + i) = o;
}

// ---- fp32 [R][Cc] -> bf16 transposed [Cc][R] ----
__global__ void tconv(const float* __restrict__ in, ushort* __restrict__ out, int R, int Cc){
  __shared__ float tile[32][33];
  int c0 = blockIdx.x * 32, r0 = blockIdx.y * 32;
  for (int i = threadIdx.y; i < 32; i += 8)
    tile[i][threadIdx.x] = in[(size_t)(r0 + i) * Cc + c0 + threadIdx.x];
  __syncthreads();
  for (int i = threadIdx.y; i < 32; i += 8)
    out[(size_t)(c0 + i) * R + r0 + threadIdx.x] = f2bf(tile[threadIdx.x][i]);
}

// ---- C[M][N] = A[M][K] @ BT[N][K]^T + bias; A,BT bf16, OUTF32 ? f32 : bf16 out ----
// 128x128 tile, BK=64, 4 waves (2x2), 16x16x32 bf16 MFMA, 4x4 frags per wave.
template<int OUTF32>
__global__ __launch_bounds__(256) void gemm_bt(const ushort* __restrict__ A, const ushort* __restrict__ BT,
                        const float* __restrict__ bias, void* __restrict__ Cout,
                        int M, int N, int K){
  constexpr int LDT = 72;  // 64 + 8 pad (row stride 144B: 16B-aligned, ~2-way banks)
  __shared__ __align__(16) ushort As[128 * LDT];
  __shared__ __align__(16) ushort Bs[128 * LDT];
  const int tid = threadIdx.x;
  const int lane = tid & 63, w = tid >> 6;
  const int wr = w >> 1, wc = w & 1;
  const int lr = lane & 15, lg = lane >> 4;
  const int m0 = blockIdx.y * 128, n0 = blockIdx.x * 128;
  f32x4 acc[4][4] = {};
  for (int k0 = 0; k0 < K; k0 += 64){
    #pragma unroll
    for (int j = 0; j < 4; ++j){
      int id = tid + j * 256;          // 1024 chunks of 16B per tile
      int row = id >> 3, seg = id & 7;
      *(int4*)&As[row * LDT + seg * 8] = *(const int4*)&A[(size_t)(m0 + row) * K + k0 + seg * 8];
      *(int4*)&Bs[row * LDT + seg * 8] = *(const int4*)&BT[(size_t)(n0 + row) * K + k0 + seg * 8];
    }
    __syncthreads();
    #pragma unroll
    for (int kk = 0; kk < 64; kk += 32){
      bf16x8 af[4], bfr[4];
      #pragma unroll
      for (int m = 0; m < 4; ++m) af[m] = *(const bf16x8*)&As[(wr*64 + m*16 + lr) * LDT + kk + lg*8];
      #pragma unroll
      for (int n = 0; n < 4; ++n) bfr[n] = *(const bf16x8*)&Bs[(wc*64 + n*16 + lr) * LDT + kk + lg*8];
      #pragma unroll
      for (int m = 0; m < 4; ++m)
        #pragma unroll
        for (int n = 0; n < 4; ++n)
          acc[m][n] = __builtin_amdgcn_mfma_f32_16x16x32_bf16(af[m], bfr[n], acc[m][n], 0, 0, 0);
    }
    __syncthreads();
  }
  // C/D layout: row = 4*(lane>>4)+i, col = lane&15  [measured m89]
  #pragma unroll
  for (int n = 0; n < 4; ++n){
    int col = n0 + wc*64 + n*16 + lr;
    float bv = bias[col];
    #pragma unroll
    for (int m = 0; m < 4; ++m){
      int rowb = m0 + wr*64 + m*16 + lg*4;
      #pragma unroll
      for (int i = 0; i < 4; ++i){
        float v = acc[m][n][i] + bv;
        if (OUTF32) ((float*)Cout)[(size_t)(rowb + i) * N + col] = v;
        else        ((ushort*)Cout)[(size_t)(rowb + i) * N + col] = f2bf(v);
      }
    }
  }
}

// ---- fused causal flash attention, bf16 MFMA ----
// block = 256 thr (4 waves), handles one (b,h) x 128 q-rows; wave w owns 32 q-rows.
// S^T = K*Q^T (softmax reduce = 2 shfl_xor); P -> LDS [q][key]; Y^T = V^T * P^T.
__global__ __launch_bounds__(256) void attn_fused(const ushort* __restrict__ qkv, ushort* __restrict__ ya){
  constexpr int LD = 72;
  __shared__ __align__(16) ushort Ks[64 * LD];      // K tile  [key][d]
  __shared__ __align__(16) ushort VsT[64 * LD];     // V tile transposed [d][key]
  __shared__ __align__(16) ushort Ps[4][32 * LD];   // per-wave P [q][key]
  const int tid = threadIdx.x;
  const int lane = tid & 63, w = tid >> 6;
  const int lr = lane & 15, lg = lane >> 4;
  const int bh = blockIdx.x >> 3, qb = blockIdx.x & 7;
  const int b = bh / H_, h = bh % H_;
  const int q0 = qb * 128;
  const ushort* Kb = qkv + (size_t)b * T_ * N3_ + C_   + h * D_;
  const ushort* Vb = qkv + (size_t)b * T_ * N3_ + 2*C_ + h * D_;

  // Q frags in registers, pre-scaled by 1/sqrt(64). Layout doubles as B-operand of K*Q^T.
  bf16x8 qf[2][2];
  #pragma unroll
  for (int n = 0; n < 2; ++n){
    int qr = q0 + w*32 + n*16 + lr;
    const ushort* qp = qkv + (size_t)(b * T_ + qr) * N3_ + h * D_;
    #pragma unroll
    for (int kk = 0; kk < 2; ++kk){
      int4 raw = *(const int4*)(qp + kk*32 + lg*8);
      const ushort* rs = (const ushort*)&raw;
      union { ushort u[8]; bf16x8 v; } t;
      #pragma unroll
      for (int i = 0; i < 8; ++i) t.u[i] = f2bf(bf2f(rs[i]) * 0.125f);
      qf[n][kk] = t.v;
    }
  }

  f32x4 yacc[4][2] = {};              // Y^T frags: [m over d][n over q]
  float mx[2] = {-1e30f, -1e30f}, lsum[2] = {0.f, 0.f};
  const int qmaxw = q0 + w*32 + 31;
  const int nkt = 2 * (qb + 1);
  for (int kt = 0; kt < nkt; ++kt){
    #pragma unroll
    for (int j = 0; j < 2; ++j){      // stage K (row-major) and V (transposed)
      int id = tid + j * 256;
      int r = id >> 3, seg = id & 7;
      *(int4*)&Ks[r * LD + seg * 8] = *(const int4*)(Kb + (size_t)(kt*64 + r) * N3_ + seg * 8);
      int4 vraw = *(const int4*)(Vb + (size_t)(kt*64 + r) * N3_ + seg * 8);
      const ushort* vs = (const ushort*)&vraw;
      #pragma unroll
      for (int i = 0; i < 8; ++i) VsT[(seg*8 + i) * LD + r] = vs[i];
    }
    __syncthreads();
    if (kt * 64 <= qmaxw){
      // S^T[key][q] frags: m over keys (4), n over q (2)
      f32x4 st[4][2] = {};
      #pragma unroll
      for (int kk = 0; kk < 2; ++kk){
        bf16x8 kf[4];
        #pragma unroll
        for (int m = 0; m < 4; ++m) kf[m] = *(const bf16x8*)&Ks[(m*16 + lr) * LD + kk*32 + lg*8];
        #pragma unroll
        for (int m = 0; m < 4; ++m)
          #pragma unroll
          for (int n = 0; n < 2; ++n)
            st[m][n] = __builtin_amdgcn_mfma_f32_16x16x32_bf16(kf[m], qf[n][kk], st[m][n], 0, 0, 0);
      }
      float corr[2];
      #pragma unroll
      for (int n = 0; n < 2; ++n){
        int q = q0 + w*32 + n*16 + lr;
        float pmax = -1e30f;
        #pragma unroll
        for (int m = 0; m < 4; ++m)
          #pragma unroll
          for (int i = 0; i < 4; ++i){
            int key = kt*64 + m*16 + lg*4 + i;
            float s = (key <= q) ? st[m][n][i] : -1e30f;
            st[m][n][i] = s;
            pmax = fmaxf(pmax, s);
          }
        pmax = fmaxf(pmax, __shfl_xor(pmax, 16));
        pmax = fmaxf(pmax, __shfl_xor(pmax, 32));
        float newm = fmaxf(mx[n], pmax);
        corr[n] = __expf(mx[n] - newm);
        mx[n] = newm;
        float ps = 0.f;
        #pragma unroll
        for (int m = 0; m < 4; ++m){
          ushort4 pk;
          #pragma unroll
          for (int i = 0; i < 4; ++i){
            float p = __expf(st[m][n][i] - newm);
            ps += p;
            ((ushort*)&pk)[i] = f2bf(p);
          }
          *(ushort4*)&Ps[w][(n*16 + lr) * LD + m*16 + lg*4] = pk;
        }
        ps += __shfl_xor(ps, 16);
        ps += __shfl_xor(ps, 32);
        lsum[n] = lsum[n] * corr[n] + ps;
      }
      #pragma unroll
      for (int m = 0; m < 4; ++m)
        #pragma unroll
        for (int n = 0; n < 2; ++n)
          #pragma unroll
          for (int i = 0; i < 4; ++i) yacc[m][n][i] *= corr[n];
      // PV: Y^T += V^T * P^T   (A from VsT[d][key], B from Ps[q][key], both contiguous b128)
      #pragma unroll
      for (int kk = 0; kk < 2; ++kk){
        bf16x8 vf[4], pf[2];
        #pragma unroll
        for (int m = 0; m < 4; ++m) vf[m] = *(const bf16x8*)&VsT[(m*16 + lr) * LD + kk*32 + lg*8];
        #pragma unroll
        for (int n = 0; n < 2; ++n) pf[n] = *(const bf16x8*)&Ps[w][(n*16 + lr) * LD + kk*32 + lg*8];
        #pragma unroll
        for (int m = 0; m < 4; ++m)
          #pragma unroll
          for (int n = 0; n < 2; ++n)
            yacc[m][n] = __builtin_amdgcn_mfma_f32_16x16x32_bf16(vf[m], pf[n], yacc[m][n], 0, 0, 0);
      }
    }
    __syncthreads();
  }
  // write ya[b, q, h*64 + d] ; lane holds d = m*16 + lg*4 + i (4 consecutive -> 8B store)
  #pragma unroll
  for (int n = 0; n < 2; ++n){
    int q = q0 + w*32 + n*16 + lr;
    float inv = 1.0f / lsum[n];
    #pragma unroll
    for (int m = 0; m < 4; ++m){
      ushort4 o;
      #pragma unroll
      for (int i = 0; i < 4; ++i) ((ushort*)&o)[i] = f2bf(yacc[m][n][i] * inv);
      *(ushort4*)&ya[(size_t)(b * T_ + q) * C_ + h * D_ + m*16 + lg*4] = o;
    }
  }
}

extern "C" void kernel_launch(void* const* d_in, const int* in_sizes, int n_in,
                              void* d_out, int out_size, void* d_ws, size_t ws_size,
                              hipStream_t stream){
  (void)in_sizes; (void)n_in; (void)out_size; (void)ws_size;
  const float* x  = (const float*)d_in[0];
  const float* Wa = (const float*)d_in[1];
  const float* ba = (const float*)d_in[2];
  const float* Wp = (const float*)d_in[3];
  const float* bp = (const float*)d_in[4];
  char* ws = (char*)d_ws;
  // ws layout (bytes):
  ushort* xb  = (ushort*)(ws);               // [8192][768] bf16 x  (reused as ya after gemm1)
  ushort* WaT = (ushort*)(ws + 12582912);    // [2304][768] bf16 W_attn^T
  ushort* WpT = (ushort*)(ws + 16121856);    // [768][768]  bf16 W_proj^T
  ushort* qkv = (ushort*)(ws + 17301504);    // [8192][2304] bf16
  ushort* ya  = xb;                          // alias: xb is dead after gemm1
  // total ws use: 55,050,240 bytes

  cvt_f32_bf16<<<dim3((M_*C_)/1024), dim3(256), 0, stream>>>(x, xb, M_*C_);
  tconv<<<dim3(N3_/32, C_/32), dim3(32,8), 0, stream>>>(Wa, WaT, C_, N3_);
  tconv<<<dim3(C_/32, C_/32), dim3(32,8), 0, stream>>>(Wp, WpT, C_, C_);
  gemm_bt<0><<<dim3(N3_/128, M_/128), dim3(256), 0, stream>>>(xb, WaT, ba, qkv, M_, N3_, C_);
  attn_fused<<<dim3(96*8), dim3(256), 0, stream>>>(qkv, ya);
  gemm_bt<1><<<dim3(C_/128, M_/128), dim3(256), 0, stream>>>(ya, WpT, bp, d_out, M_, C_, C_);
}